// Round 6
// baseline (296.236 us; speedup 1.0000x reference)
//
#include <hip/hip_runtime.h>

#define T_LEN  16384
#define NTHR   256             // 4 waves; one row per block, 4 chunk-iterations
#define NWAVE  4
#define CH4    1024            // float4s per chunk (4096 floats)
#define ROW4   4096            // float4s per row
#define PAD4(i) ((i) + ((i) >> 4))

// Causal unbiased-EMA instance norm. One 256-thread block per (b,c) row,
// walking the row in 4 chunks of 4096 with EXACT carried EMA state (no halo).
// Per chunk: prefetch next chunk to regs (overlaps everything below) ->
// stage regs->LDS (padded) -> per-thread 16-elem scan -> wave Hillis-Steele
// (decay a^(16*2^k)) -> 4-wave LDS fold (+ chunk carry) -> fused normalize
//   out = (x*w - s1) * rsqrt(s2*w - s1^2 + eps*w^2)
// -> LDS -> full-line coalesced store (R4 proved strided stores cause 3.4x
// RMW write amplification; all global I/O is lane-contiguous float4 here).

__device__ __forceinline__ void process16(float4 (&xv)[4], float s1, float s2, float w) {
    const float A    = 0.99f;
    const float OMA  = (float)(1.0 - 0.99);
    const float EPSF = 1e-5f;
#pragma unroll
    for (int i = 0; i < 4; ++i) {
        float4 xq = xv[i];
        float4 oq;
#pragma unroll
        for (int e = 0; e < 4; ++e) {
            float xi = (e == 0) ? xq.x : (e == 1) ? xq.y : (e == 2) ? xq.z : xq.w;
            float t = OMA * xi;
            s1 = fmaf(A, s1, t);
            s2 = fmaf(A, s2, t * xi);
            w  = fmaf(A, w, OMA);
            float numer = fmaf(xi, w, -s1);
            float arg   = fmaf(s2, w, fmaf(-s1, s1, EPSF * (w * w)));
            float rs    = __builtin_amdgcn_rsqf(arg);
            float o     = numer * rs;
            if (e == 0) oq.x = o; else if (e == 1) oq.y = o; else if (e == 2) oq.z = o; else oq.w = o;
        }
        xv[i] = oq;
    }
}

__global__ __launch_bounds__(NTHR, 8)
void ema_norm_kernel(const float* __restrict__ x, float* __restrict__ y) {
    const float A   = 0.99f;
    const float Kf  = (float)((double)((float)(1.0 - 0.99)) / (1.0 - (double)0.99f));

    const int row  = blockIdx.x;
    const int tid  = threadIdx.x;
    const int lane = tid & 63;
    const int wid  = tid >> 6;

    const float4* __restrict__ xr4 = reinterpret_cast<const float4*>(x) + (size_t)row * ROW4;
    float4*       __restrict__ yr4 = reinterpret_cast<float4*>(y) + (size_t)row * ROW4;

    __shared__ float4 buf[CH4 + CH4 / 16];   // 1088 float4 = 17.4 KB
    __shared__ float  tW1[NWAVE], tW2[NWAVE];

    // d[k] = alpha^(16*2^k): all-literal repeated squaring -> constant-folded
    float a16 = A;
#pragma unroll
    for (int i = 0; i < 4; ++i) a16 *= a16;   // alpha^16
    float d[10];
    d[0] = a16;
#pragma unroll
    for (int k = 1; k < 10; ++k) d[k] = d[k - 1] * d[k - 1];
    const float Dw = d[6];                    // alpha^1024 (one wave's span)

    // per-thread decay factors
    float fdec = 1.f;                         // alpha^(16*lane)
#pragma unroll
    for (int k = 0; k < 6; ++k) if (lane & (1 << k)) fdec *= d[k];
    float pwtid = 1.f;                        // alpha^(16*tid), tid < 256
#pragma unroll
    for (int k = 0; k < 8; ++k) if (tid & (1 << k)) pwtid *= d[k];

    float C1 = 0.f, C2 = 0.f;                 // exact chunk-carry state

    float4 rA[4], rB[4];
#pragma unroll
    for (int k = 0; k < 4; ++k) rA[k] = xr4[tid + NTHR * k];   // chunk 0

    auto do_iter = [&](float4 (&rc)[4], float4 (&rn)[4], int it, float pwit, bool prefetch) {
        // 1) issue next-chunk loads (plain VGPR loads stay in flight across barriers)
        if (prefetch) {
#pragma unroll
            for (int k = 0; k < 4; ++k) rn[k] = xr4[(it + 1) * CH4 + tid + NTHR * k];
        }
        // 2) stage current chunk into LDS (I/O layout)
#pragma unroll
        for (int k = 0; k < 4; ++k) buf[PAD4(tid + NTHR * k)] = rc[k];
        __syncthreads();

        // 3) own 16 contiguous elems, local EMA scan from zero
        float4 xv[4];
#pragma unroll
        for (int c = 0; c < 4; ++c) xv[c] = buf[PAD4(4 * tid + c)];
        const float OMA = (float)(1.0 - 0.99);
        float s1 = 0.f, s2 = 0.f;
#pragma unroll
        for (int i = 0; i < 4; ++i) {
            float t;
            t = OMA * xv[i].x; s1 = fmaf(A, s1, t); s2 = fmaf(A, s2, t * xv[i].x);
            t = OMA * xv[i].y; s1 = fmaf(A, s1, t); s2 = fmaf(A, s2, t * xv[i].y);
            t = OMA * xv[i].z; s1 = fmaf(A, s1, t); s2 = fmaf(A, s2, t * xv[i].z);
            t = OMA * xv[i].w; s1 = fmaf(A, s1, t); s2 = fmaf(A, s2, t * xv[i].w);
        }

        // 4) wave-level inclusive scan (Hillis-Steele with decay)
        float v1 = s1, v2 = s2;
#pragma unroll
        for (int k = 0; k < 6; ++k) {
            const int off = 1 << k;
            float o1 = __shfl_up(v1, off, 64);
            float o2 = __shfl_up(v2, off, 64);
            if (lane >= off) { v1 = fmaf(d[k], o1, v1); v2 = fmaf(d[k], o2, v2); }
        }
        float c1 = __shfl_up(v1, 1, 64);
        float c2 = __shfl_up(v2, 1, 64);
        if (lane == 0) { c1 = 0.f; c2 = 0.f; }

        // 5) cross-wave fold with chunk carry: S_{v+1} = Dw*S_v + T_v, S_0 = C
        if (lane == 63) { tW1[wid] = v1; tW2[wid] = v2; }
        __syncthreads();
        float W1 = C1, W2 = C2;
        float myW1 = C1, myW2 = C2;
#pragma unroll
        for (int v = 0; v < NWAVE; ++v) {
            if (v == wid) { myW1 = W1; myW2 = W2; }
            W1 = fmaf(Dw, W1, tW1[v]);
            W2 = fmaf(Dw, W2, tW2[v]);
        }
        C1 = W1; C2 = W2;                         // exact carry to next chunk
        c1 = fmaf(myW1, fdec, c1);
        c2 = fmaf(myW2, fdec, c2);

        // 6) bias weight w0 = K*(1 - alpha^(16*m)), m = 256*it + tid
        //    (m==0 -> pw==1 -> w0==0 exactly: reference-exact start)
        float w0 = Kf * (1.f - pwtid * pwit);

        // 7) fused normalize in place, transpose out through LDS, store
        process16(xv, c1, c2, w0);
#pragma unroll
        for (int c = 0; c < 4; ++c) buf[PAD4(4 * tid + c)] = xv[c];
        __syncthreads();
#pragma unroll
        for (int k = 0; k < 4; ++k) yr4[it * CH4 + tid + NTHR * k] = buf[PAD4(tid + NTHR * k)];
        __syncthreads();                          // buf reuse fence for next iter
    };

    const float p1 = d[8];                        // alpha^4096
    const float p2 = d[9];                        // alpha^8192
    const float p3 = d[8] * d[9];                 // alpha^12288
    do_iter(rA, rB, 0, 1.0f, true);
    do_iter(rB, rA, 1, p1,   true);
    do_iter(rA, rB, 2, p2,   true);
    do_iter(rB, rA, 3, p3,   false);
}

extern "C" void kernel_launch(void* const* d_in, const int* in_sizes, int n_in,
                              void* d_out, int out_size, void* d_ws, size_t ws_size,
                              hipStream_t stream) {
    const float* x = (const float*)d_in[0];
    float* y = (float*)d_out;
    const int rows = in_sizes[0] / T_LEN;         // B*C = 2048
    ema_norm_kernel<<<rows, NTHR, 0, stream>>>(x, y);
}

// Round 7
// 236.288 us; speedup vs baseline: 1.2537x; 1.2537x over previous
//
#include <hip/hip_runtime.h>

#define NTHR   256
#define NWAVE  4
#define CH4    1024            // float4s per chunk (4096 floats)
#define ROW4   4096            // float4s per row
#define PAD4(i) ((i) + ((i) >> 4))

// Causal unbiased-EMA instance norm. One 256-thread block per (b,c) row,
// 4 chunks of 4096 with EXACT carried EMA state. Per chunk: prefetch next
// chunk into named float4 registers (overlaps scan+normalize below) ->
// stage regs->padded LDS -> per-thread 16-elem scan -> wave Hillis-Steele
// -> 4-wave fold (+carry) -> fused normalize -> LDS -> full-line store.
// R6 LESSON: array-by-reference lambda params sent the double-buffer to
// scratch (VGPR=32, +280MB HBM traffic). Everything here is named scalars
// + textual macros; decays are constexpr literals.

constexpr float fsq(float v) { return v * v; }
constexpr float A_    = 0.99f;
constexpr float OMA_  = (float)(1.0 - 0.99);
constexpr float D16   = fsq(fsq(fsq(fsq(A_))));  // a^16
constexpr float D32   = fsq(D16);
constexpr float D64   = fsq(D32);
constexpr float D128  = fsq(D64);
constexpr float D256  = fsq(D128);
constexpr float D512  = fsq(D256);
constexpr float D1K   = fsq(D512);               // a^1024
constexpr float D2K   = fsq(D1K);
constexpr float D4K   = fsq(D2K);                // a^4096
constexpr float D8K   = fsq(D4K);                // a^8192
constexpr float D12K  = D4K * D8K;               // a^12288
constexpr float KF    = (float)((double)OMA_ / (1.0 - (double)A_));

__device__ __forceinline__ float4 norm4(float4 xq, float& s1, float& s2, float& w) {
    constexpr float EPSF = 1e-5f;
    float4 oq;
    { float xi = xq.x; float t = OMA_*xi; s1 = fmaf(A_,s1,t); s2 = fmaf(A_,s2,t*xi);
      w = fmaf(A_,w,OMA_);
      float nu = fmaf(xi,w,-s1); float ag = fmaf(s2,w,fmaf(-s1,s1,EPSF*(w*w)));
      oq.x = nu * __builtin_amdgcn_rsqf(ag); }
    { float xi = xq.y; float t = OMA_*xi; s1 = fmaf(A_,s1,t); s2 = fmaf(A_,s2,t*xi);
      w = fmaf(A_,w,OMA_);
      float nu = fmaf(xi,w,-s1); float ag = fmaf(s2,w,fmaf(-s1,s1,EPSF*(w*w)));
      oq.y = nu * __builtin_amdgcn_rsqf(ag); }
    { float xi = xq.z; float t = OMA_*xi; s1 = fmaf(A_,s1,t); s2 = fmaf(A_,s2,t*xi);
      w = fmaf(A_,w,OMA_);
      float nu = fmaf(xi,w,-s1); float ag = fmaf(s2,w,fmaf(-s1,s1,EPSF*(w*w)));
      oq.z = nu * __builtin_amdgcn_rsqf(ag); }
    { float xi = xq.w; float t = OMA_*xi; s1 = fmaf(A_,s1,t); s2 = fmaf(A_,s2,t*xi);
      w = fmaf(A_,w,OMA_);
      float nu = fmaf(xi,w,-s1); float ag = fmaf(s2,w,fmaf(-s1,s1,EPSF*(w*w)));
      oq.w = nu * __builtin_amdgcn_rsqf(ag); }
    return oq;
}

#define ACC4(q) { float t; \
    t = OMA_*(q).x; s1 = fmaf(A_,s1,t); s2 = fmaf(A_,s2,t*(q).x); \
    t = OMA_*(q).y; s1 = fmaf(A_,s1,t); s2 = fmaf(A_,s2,t*(q).y); \
    t = OMA_*(q).z; s1 = fmaf(A_,s1,t); s2 = fmaf(A_,s2,t*(q).z); \
    t = OMA_*(q).w; s1 = fmaf(A_,s1,t); s2 = fmaf(A_,s2,t*(q).w); }

#define WS(OFF, DK) { float o1 = __shfl_up(v1, OFF, 64), o2 = __shfl_up(v2, OFF, 64); \
    if (lane >= OFF) { v1 = fmaf(DK, o1, v1); v2 = fmaf(DK, o2, v2); } }

#define EMA_ITER(IT, CA,CB,CC,CD, NA,NB,NC,ND, PREF, PWIT) do { \
    if (PREF) { const float4* p = xr4 + (IT+1)*CH4 + tid; \
        NA = p[0]; NB = p[256]; NC = p[512]; ND = p[768]; } \
    buf[PAD4(tid)]     = CA; buf[PAD4(tid+256)] = CB; \
    buf[PAD4(tid+512)] = CC; buf[PAD4(tid+768)] = CD; \
    __syncthreads(); \
    float4 x0 = buf[PAD4(4*tid)],   x1 = buf[PAD4(4*tid+1)]; \
    float4 x2 = buf[PAD4(4*tid+2)], x3 = buf[PAD4(4*tid+3)]; \
    float s1 = 0.f, s2 = 0.f; \
    ACC4(x0); ACC4(x1); ACC4(x2); ACC4(x3); \
    float v1 = s1, v2 = s2; \
    WS(1, D16) WS(2, D32) WS(4, D64) WS(8, D128) WS(16, D256) WS(32, D512) \
    float e1 = __shfl_up(v1, 1, 64), e2 = __shfl_up(v2, 1, 64); \
    if (lane == 0) { e1 = 0.f; e2 = 0.f; } \
    if (lane == 63) { tW1[wid] = v1; tW2[wid] = v2; } \
    __syncthreads(); \
    float W1 = C1, W2 = C2, myW1 = C1, myW2 = C2; \
    if (wid == 0) { myW1 = W1; myW2 = W2; } \
    W1 = fmaf(D1K, W1, tW1[0]); W2 = fmaf(D1K, W2, tW2[0]); \
    if (wid == 1) { myW1 = W1; myW2 = W2; } \
    W1 = fmaf(D1K, W1, tW1[1]); W2 = fmaf(D1K, W2, tW2[1]); \
    if (wid == 2) { myW1 = W1; myW2 = W2; } \
    W1 = fmaf(D1K, W1, tW1[2]); W2 = fmaf(D1K, W2, tW2[2]); \
    if (wid == 3) { myW1 = W1; myW2 = W2; } \
    W1 = fmaf(D1K, W1, tW1[3]); W2 = fmaf(D1K, W2, tW2[3]); \
    C1 = W1; C2 = W2; \
    float cc1 = fmaf(myW1, fdec, e1), cc2 = fmaf(myW2, fdec, e2); \
    float ww = KF * (1.f - pwtid * (PWIT)); \
    x0 = norm4(x0, cc1, cc2, ww); x1 = norm4(x1, cc1, cc2, ww); \
    x2 = norm4(x2, cc1, cc2, ww); x3 = norm4(x3, cc1, cc2, ww); \
    buf[PAD4(4*tid)]   = x0; buf[PAD4(4*tid+1)] = x1; \
    buf[PAD4(4*tid+2)] = x2; buf[PAD4(4*tid+3)] = x3; \
    __syncthreads(); \
    float4* q = yr4 + (IT)*CH4 + tid; \
    q[0] = buf[PAD4(tid)];     q[256] = buf[PAD4(tid+256)]; \
    q[512] = buf[PAD4(tid+512)]; q[768] = buf[PAD4(tid+768)]; \
    __syncthreads(); \
} while (0)

__global__ __launch_bounds__(NTHR, 4)
void ema_norm_kernel(const float* __restrict__ x, float* __restrict__ y) {
    const int tid  = threadIdx.x;
    const int lane = tid & 63;
    const int wid  = tid >> 6;

    const float4* __restrict__ xr4 = reinterpret_cast<const float4*>(x) + (size_t)blockIdx.x * ROW4;
    float4*       __restrict__ yr4 = reinterpret_cast<float4*>(y) + (size_t)blockIdx.x * ROW4;

    __shared__ float4 buf[CH4 + CH4 / 16];       // 1088 float4 = 17.4 KB
    __shared__ float  tW1[NWAVE], tW2[NWAVE];

    // fdec = alpha^(16*lane); pwtid = alpha^(16*tid)
    float fdec = 1.f;
    if (lane & 1)  fdec *= D16;
    if (lane & 2)  fdec *= D32;
    if (lane & 4)  fdec *= D64;
    if (lane & 8)  fdec *= D128;
    if (lane & 16) fdec *= D256;
    if (lane & 32) fdec *= D512;
    float pwtid = fdec;
    if (tid & 64)  pwtid *= D1K;
    if (tid & 128) pwtid *= D2K;

    float C1 = 0.f, C2 = 0.f;                    // exact chunk carry

    float4 a0, a1, a2, a3, b0, b1, b2, b3;
    { const float4* p = xr4 + tid; a0 = p[0]; a1 = p[256]; a2 = p[512]; a3 = p[768]; }

    EMA_ITER(0, a0,a1,a2,a3, b0,b1,b2,b3, true,  1.0f);
    EMA_ITER(1, b0,b1,b2,b3, a0,a1,a2,a3, true,  D4K);
    EMA_ITER(2, a0,a1,a2,a3, b0,b1,b2,b3, true,  D8K);
    EMA_ITER(3, b0,b1,b2,b3, a0,a1,a2,a3, false, D12K);
}

extern "C" void kernel_launch(void* const* d_in, const int* in_sizes, int n_in,
                              void* d_out, int out_size, void* d_ws, size_t ws_size,
                              hipStream_t stream) {
    const float* x = (const float*)d_in[0];
    float* y = (float*)d_out;
    const int rows = in_sizes[0] / 16384;        // B*C = 2048
    ema_norm_kernel<<<rows, NTHR, 0, stream>>>(x, y);
}